// Round 5
// baseline (247.398 us; speedup 1.0000x reference)
//
#include <hip/hip_runtime.h>
#include <hip/hip_bf16.h>

#define NN 50000
#define EE 800000
#define NEG 0.2f

using u32 = unsigned int;

// ---- K0: merged precompute ----
// blocks 0..127 : Wz[k][256] = W_gat row k folded with blockdiag(W_c[0:64])
// block 128     : Wt[16][4], cvec[64] (ns-pool @ W_c + b_gat @ W_c + b_c folded)
// block 129     : av[128][8] = W_gat folded with att_src/att_dst
__global__ __launch_bounds__(256) void k_pre_all(
        const float* __restrict__ Wg, const float* __restrict__ W_c,
        const float* __restrict__ W_edge, const float* __restrict__ att_edge,
        const float* __restrict__ b_c, const float* __restrict__ ns,
        const float* __restrict__ b_gat,
        const float* __restrict__ att_src, const float* __restrict__ att_dst,
        float* __restrict__ Wz, float* __restrict__ Wt,
        float* __restrict__ cvec, float* __restrict__ av){
  int bid = blockIdx.x, tid = threadIdx.x;
  if (bid < 128){
    __shared__ float sWg[256];
    __shared__ float sWc[64*64];
    sWg[tid] = Wg[bid*256 + tid];
    for (int i = tid; i < 4096; i += 256) sWc[i] = W_c[i];
    __syncthreads();
    int h = tid >> 6, j = tid & 63;
    float s = 0.f;
    #pragma unroll 8
    for (int c = 0; c < 64; c++) s += sWg[h*64 + c] * sWc[c*64 + j];
    Wz[bid*256 + tid] = s;
  } else if (bid == 128){
    if (tid < 64){
      int d = tid >> 2, h = tid & 3;
      float s = 0.f;
      for (int c = 0; c < 64; c++) s += W_edge[d*256 + h*64 + c] * att_edge[h*64 + c];
      Wt[d*4 + h] = s;
    } else if (tid < 128){
      int j = tid - 64;
      float s = b_c[j];
      for (int d = 0; d < 16; d++) s += ns[d >> 1] * W_c[(64 + d)*64 + j];
      for (int c = 0; c < 64; c++) s += b_gat[c] * W_c[c*64 + j];
      cvec[j] = s;
    }
  } else {
    for (int i = tid; i < 1024; i += 256){
      int k = i >> 3, o = i & 7, h = o & 3;
      const float* att = (o < 4) ? att_src : att_dst;
      float s = 0.f;
      for (int c = 0; c < 64; c++) s += Wg[k*256 + h*64 + c] * att[h*64 + c];
      av[i] = s;
    }
  }
}

// ---- K1: zs = x @ Wz (bf16 store) + fused a_src/a_dst + deg histogram AT END ----
// BM=32: 1563 blocks (6/CU). Bs XOR-swizzled (f4^=(f4>>3)&1) for conflict-free
// ds_read_b128; As stride 36 (pad) for conflict-free stage writes; register
// prefetch of next K-tile overlaps global loads with compute.
#define BM 32
#define BK 16
__global__ __launch_bounds__(256) void k_gemm(const float* __restrict__ x,
                                              const float* __restrict__ Wz,
                                              const float* __restrict__ av,
                                              const int* __restrict__ dsts,
                                              __hip_bfloat16* __restrict__ zs,
                                              float* __restrict__ a_src,
                                              float* __restrict__ a_dst,
                                              u32* __restrict__ deg){
  __shared__ float As[BK*36];
  __shared__ float Bs[BK*256];
  __shared__ float sav[1024];
  int tid = threadIdx.x;
  int n0 = blockIdx.x * BM;
  for (int i = tid; i < 1024; i += 256) sav[i] = av[i];

  int tc = tid & 31, tr = tid >> 5;       // compute: rows tr*4..+3, cols tc*8..+7
  int ar = tid >> 3, ak = (tid & 7) * 2;  // As stage: row ar, k-pair ak
  int oa = tid & 7;                       // adot: row ar, output slot oa
  int an = n0 + ar; if (an >= NN) an = NN - 1;
  const float* xa = x + (size_t)an*128 + ak;

  // prologue prefetch (k0 = 0)
  float2 va = *(const float2*)(xa);
  float4 vb[4];
  #pragma unroll
  for (int i = 0; i < 4; i++){
    int f4 = i*256 + tid;
    vb[i] = *(const float4*)(Wz + (size_t)f4*4);
  }

  float pa = 0.f;
  float acc[4][8];
  #pragma unroll
  for (int i = 0; i < 4; i++)
    #pragma unroll
    for (int j = 0; j < 8; j++) acc[i][j] = 0.f;

  for (int k0 = 0; k0 < 128; k0 += BK){
    As[ak*36 + ar]     = va.x;
    As[(ak+1)*36 + ar] = va.y;
    #pragma unroll
    for (int i = 0; i < 4; i++){
      int f4 = i*256 + tid;
      int f4s = f4 ^ ((f4 >> 3) & 1);
      *(float4*)&Bs[f4s*4] = vb[i];
    }
    __syncthreads();
    if (k0 + BK < 128){
      va = *(const float2*)(xa + k0 + BK);
      #pragma unroll
      for (int i = 0; i < 4; i++){
        int f4 = i*256 + tid;
        vb[i] = *(const float4*)(Wz + (size_t)(k0+BK)*256 + f4*4);
      }
    }
    #pragma unroll
    for (int kk = 0; kk < BK; kk++){
      float4 a4 = *(float4*)&As[kk*36 + tr*4];
      int r0 = kk*64 + tc*2;
      int r0s = r0 ^ ((r0 >> 3) & 1);
      int r1 = r0 + 1;
      int r1s = r1 ^ ((r1 >> 3) & 1);
      float4 b0 = *(float4*)&Bs[r0s*4];
      float4 b1 = *(float4*)&Bs[r1s*4];
      float a[4] = {a4.x, a4.y, a4.z, a4.w};
      float b[8] = {b0.x,b0.y,b0.z,b0.w,b1.x,b1.y,b1.z,b1.w};
      #pragma unroll
      for (int i = 0; i < 4; i++)
        #pragma unroll
        for (int j = 0; j < 8; j++) acc[i][j] += a[i]*b[j];
      pa += As[kk*36 + ar] * sav[(k0+kk)*8 + oa];
    }
    __syncthreads();
  }
  #pragma unroll
  for (int i = 0; i < 4; i++){
    int n = n0 + tr*4 + i;
    if (n < NN){
      alignas(16) __hip_bfloat16 tmp[8];
      #pragma unroll
      for (int j = 0; j < 8; j++) tmp[j] = __float2bfloat16(acc[i][j]);
      *(uint4*)(zs + (size_t)n*256 + tc*8) = *(uint4*)tmp;
    }
  }
  {
    int na = n0 + ar;
    if (na < NN){
      if (oa < 4) a_src[(size_t)na*4 + oa] = pa;
      else        a_dst[(size_t)na*4 + (oa-4)] = pa;
    }
  }
  // deg histogram LAST: fire-and-forget before endpgm, no waitcnt behind it
  {
    int g = blockIdx.x*256 + tid;
    if (g < EE/4){
      int4 d4 = *(const int4*)(dsts + (size_t)g*4);
      atomicAdd(&deg[d4.x], 1u);
      atomicAdd(&deg[d4.y], 1u);
      atomicAdd(&deg[d4.z], 1u);
      atomicAdd(&deg[d4.w], 1u);
    }
  }
}

// ---- K3a/K3b: two-level exclusive scan of deg -> offs (+ cnt zeroing) ----
__global__ __launch_bounds__(1024) void k_scan1(const u32* __restrict__ deg,
                                                u32* __restrict__ offs, u32* __restrict__ bsum){
  __shared__ u32 sd[1024];
  int t = threadIdx.x;
  int i = blockIdx.x*1024 + t;
  u32 v = (i < NN) ? deg[i] : 0u;
  sd[t] = v; __syncthreads();
  for (int off = 1; off < 1024; off <<= 1){
    u32 u = (t >= off) ? sd[t-off] : 0u;
    __syncthreads();
    sd[t] += u;
    __syncthreads();
  }
  if (i < NN) offs[i] = sd[t] - v;
  if (t == 1023) bsum[blockIdx.x] = sd[1023];
}

__global__ __launch_bounds__(1024) void k_scan2(u32* __restrict__ offs, const u32* __restrict__ bsum,
                                                u32* __restrict__ cnt){
  int b = blockIdx.x;
  u32 p = 0;
  for (int j = 0; j < b; j++) p += bsum[j];
  int i = b*1024 + threadIdx.x;
  if (i < NN){ offs[i] += p; cnt[i] = 0u; }
  if (i == NN-1){
    u32 tot = p;
    for (int j = b; j < 49; j++) tot += bsum[j];
    offs[NN] = tot;
  }
}

// ---- K4: per-edge logits + leaky_relu, written DIRECTLY in CSR order ----
__global__ __launch_bounds__(256) void k_edge(const float* __restrict__ qraw,
        const float* __restrict__ eattr, const int* __restrict__ eidx,
        const float* __restrict__ Wq1, const float* __restrict__ bq1,
        const float* __restrict__ Wq2, const float* __restrict__ bq2,
        const float* __restrict__ Wt,
        const float* __restrict__ a_src, const float* __restrict__ a_dst,
        const u32* __restrict__ offs, u32* __restrict__ cnt,
        float* __restrict__ alpha_csr, u32* __restrict__ srcs_csr){
  __shared__ float sWq1[32], sbq1[8], sWq2[128], sbq2[16], sWt[64];
  int tid = threadIdx.x;
  if (tid < 32) sWq1[tid] = Wq1[tid];
  else if (tid < 40)  sbq1[tid-32]  = bq1[tid-32];
  else if (tid < 168) sWq2[tid-40]  = Wq2[tid-40];
  else if (tid < 184) sbq2[tid-168] = bq2[tid-168];
  else if (tid < 248) sWt[tid-184]  = Wt[tid-184];
  __syncthreads();
  int e = blockIdx.x*256 + tid;
  if (e >= EE) return;

  float4 qr = *(const float4*)(qraw + (size_t)e*4);
  float t1[8];
  #pragma unroll
  for (int j = 0; j < 8; j++){
    float s = sbq1[j] + qr.x*sWq1[j] + qr.y*sWq1[8+j] + qr.z*sWq1[16+j] + qr.w*sWq1[24+j];
    t1[j] = fmaxf(s, 0.f);
  }
  float ae[4] = {0.f,0.f,0.f,0.f};
  const float* ea = eattr + (size_t)e*16;
  #pragma unroll
  for (int d = 0; d < 16; d++){
    float q = sbq2[d];
    #pragma unroll
    for (int j = 0; j < 8; j++) q += t1[j]*sWq2[j*16 + d];
    float v = ea[d] + q;
    #pragma unroll
    for (int h = 0; h < 4; h++) ae[h] += v * sWt[d*4 + h];
  }
  int src = eidx[e], dst = eidx[EE + e];
  float4 as4 = *(const float4*)(a_src + (size_t)src*4);
  float4 ad4 = *(const float4*)(a_dst + (size_t)dst*4);
  float4 out;
  float* po = (float*)&out;
  float av4[4] = {as4.x + ad4.x + ae[0], as4.y + ad4.y + ae[1],
                  as4.z + ad4.z + ae[2], as4.w + ad4.w + ae[3]};
  #pragma unroll
  for (int hh = 0; hh < 4; hh++){
    float a = av4[hh];
    po[hh] = (a >= 0.f) ? a : NEG*a;
  }
  u32 pos = offs[dst] + atomicAdd(&cnt[dst], 1u);
  ((float4*)alpha_csr)[pos] = out;
  srcs_csr[pos] = (u32)src;
}

// ---- K5: per-node aggregation, NO max subtraction (logits bounded), 4x unroll ----
__global__ __launch_bounds__(256) void k_agg(const __hip_bfloat16* __restrict__ zs,
        const u32* __restrict__ srcs_csr, const u32* __restrict__ offs,
        const float* __restrict__ alpha_csr,
        const float* __restrict__ cvec, float* __restrict__ out){
  int tid = threadIdx.x;
  int w = tid >> 6, lane = tid & 63;
  int n = blockIdx.x*4 + w;       // grid = NN/4 exactly
  int h = lane >> 4;              // this lane's head (channels lane*4..lane*4+3)
  u32 p0 = offs[n], p1 = offs[n+1];
  float d = 0.f;
  float a0 = 0.f, a1 = 0.f, a2 = 0.f, a3 = 0.f;
  u32 p = p0;
  for (; p + 4 <= p1; p += 4){
    u32 s0 = srcs_csr[p+0], s1 = srcs_csr[p+1], s2 = srcs_csr[p+2], s3 = srcs_csr[p+3];
    float al0 = alpha_csr[(size_t)(p+0)*4 + h];
    float al1 = alpha_csr[(size_t)(p+1)*4 + h];
    float al2 = alpha_csr[(size_t)(p+2)*4 + h];
    float al3 = alpha_csr[(size_t)(p+3)*4 + h];
    uint2 v0 = *(const uint2*)(zs + (size_t)s0*256 + lane*4);
    uint2 v1 = *(const uint2*)(zs + (size_t)s1*256 + lane*4);
    uint2 v2 = *(const uint2*)(zs + (size_t)s2*256 + lane*4);
    uint2 v3 = *(const uint2*)(zs + (size_t)s3*256 + lane*4);
    float w0 = __expf(al0), w1 = __expf(al1), w2 = __expf(al2), w3 = __expf(al3);
    a0 += w0*__uint_as_float(v0.x << 16)        + w1*__uint_as_float(v1.x << 16)
        + w2*__uint_as_float(v2.x << 16)        + w3*__uint_as_float(v3.x << 16);
    a1 += w0*__uint_as_float(v0.x & 0xffff0000u)+ w1*__uint_as_float(v1.x & 0xffff0000u)
        + w2*__uint_as_float(v2.x & 0xffff0000u)+ w3*__uint_as_float(v3.x & 0xffff0000u);
    a2 += w0*__uint_as_float(v0.y << 16)        + w1*__uint_as_float(v1.y << 16)
        + w2*__uint_as_float(v2.y << 16)        + w3*__uint_as_float(v3.y << 16);
    a3 += w0*__uint_as_float(v0.y & 0xffff0000u)+ w1*__uint_as_float(v1.y & 0xffff0000u)
        + w2*__uint_as_float(v2.y & 0xffff0000u)+ w3*__uint_as_float(v3.y & 0xffff0000u);
    d  += (w0 + w1) + (w2 + w3);
  }
  for (; p < p1; p++){
    u32 s0 = srcs_csr[p];
    float al = alpha_csr[(size_t)p*4 + h];
    uint2 v0 = *(const uint2*)(zs + (size_t)s0*256 + lane*4);
    float w0 = __expf(al);
    a0 += w0*__uint_as_float(v0.x << 16);
    a1 += w0*__uint_as_float(v0.x & 0xffff0000u);
    a2 += w0*__uint_as_float(v0.y << 16);
    a3 += w0*__uint_as_float(v0.y & 0xffff0000u);
    d  += w0;
  }
  float inv = (d > 0.f) ? 0.25f / d : 0.f;
  a0 *= inv; a1 *= inv; a2 *= inv; a3 *= inv;
  // head mean: sum over the 4 head-groups of 16 lanes
  a0 += __shfl_xor(a0, 16); a1 += __shfl_xor(a1, 16);
  a2 += __shfl_xor(a2, 16); a3 += __shfl_xor(a3, 16);
  a0 += __shfl_xor(a0, 32); a1 += __shfl_xor(a1, 32);
  a2 += __shfl_xor(a2, 32); a3 += __shfl_xor(a3, 32);
  if (lane < 16){
    float4 cv = *(const float4*)(cvec + lane*4);
    float4 o4;
    o4.x = fmaxf(a0 + cv.x, 0.f);
    o4.y = fmaxf(a1 + cv.y, 0.f);
    o4.z = fmaxf(a2 + cv.z, 0.f);
    o4.w = fmaxf(a3 + cv.w, 0.f);
    *(float4*)(out + (size_t)n*64 + lane*4) = o4;
  }
}

extern "C" void kernel_launch(void* const* d_in, const int* in_sizes, int n_in,
                              void* d_out, int out_size, void* d_ws, size_t ws_size,
                              hipStream_t stream){
  const float* x       = (const float*)d_in[0];
  const int*   eidx    = (const int*)d_in[1];
  const float* eattr   = (const float*)d_in[2];
  const float* qraw    = (const float*)d_in[3];
  const float* ns      = (const float*)d_in[4];
  const float* Wg      = (const float*)d_in[5];
  const float* att_src = (const float*)d_in[6];
  const float* att_dst = (const float*)d_in[7];
  const float* W_edge  = (const float*)d_in[8];
  const float* att_edge= (const float*)d_in[9];
  const float* b_gat   = (const float*)d_in[10];
  const float* Wq1     = (const float*)d_in[11];
  const float* bq1     = (const float*)d_in[12];
  const float* Wq2     = (const float*)d_in[13];
  const float* bq2     = (const float*)d_in[14];
  const float* W_c     = (const float*)d_in[15];
  const float* b_c     = (const float*)d_in[16];
  float* out = (float*)d_out;

  char* ws = (char*)d_ws;
  __hip_bfloat16* zs = (__hip_bfloat16*)ws;            // 25,600,000 B
  float* a_src    = (float*)(ws + 25600000);           //    800,000 B
  float* a_dst    = (float*)(ws + 26400000);           //    800,000 B
  float* alpha_csr= (float*)(ws + 27200000);           // 12,800,000 B
  u32* srcs_csr   = (u32*)(ws + 40000000);             //  3,200,000 B
  u32* deg        = (u32*)(ws + 43200000);             //    200,000 B
  u32* offs       = (u32*)(ws + 43400000);             //    200,064 B
  u32* cnt        = (u32*)(ws + 43600064);             //    200,000 B
  u32* bsum       = (u32*)(ws + 43800064);             //        256 B
  float* Wt       = (float*)(ws + 43800320);           //        256 B
  float* cvec     = (float*)(ws + 43800576);           //        256 B
  float* Wz       = (float*)(ws + 43800832);           //    131,072 B
  float* av       = (float*)(ws + 43931904);           //      4,096 B

  hipMemsetAsync(deg, 0, 200000, stream);

  k_pre_all<<<130,  256, 0, stream>>>(Wg, W_c, W_edge, att_edge, b_c, ns, b_gat,
                                      att_src, att_dst, Wz, Wt, cvec, av);
  k_gemm   <<<1563, 256, 0, stream>>>(x, Wz, av, eidx + EE, zs, a_src, a_dst, deg);
  k_scan1  <<<49,  1024, 0, stream>>>(deg, offs, bsum);
  k_scan2  <<<49,  1024, 0, stream>>>(offs, bsum, cnt);
  k_edge   <<<3125, 256, 0, stream>>>(qraw, eattr, eidx, Wq1, bq1, Wq2, bq2, Wt,
                                      a_src, a_dst, offs, cnt, alpha_csr, srcs_csr);
  k_agg    <<<12500,256, 0, stream>>>(zs, srcs_csr, offs, alpha_csr, cvec, out);
}

// Round 6
// 238.105 us; speedup vs baseline: 1.0390x; 1.0390x over previous
//
#include <hip/hip_runtime.h>
#include <hip/hip_bf16.h>

#define NN 50000
#define EE 800000
#define NEG 0.2f

using u32 = unsigned int;
typedef short short4v __attribute__((ext_vector_type(4)));
typedef float f32x4 __attribute__((ext_vector_type(4)));

__device__ __forceinline__ unsigned short f2bf(float f){
  u32 b = __float_as_uint(f);
  b += 0x7FFFu + ((b >> 16) & 1u);        // RNE; inputs finite
  return (unsigned short)(b >> 16);
}

// ---- K0: merged precompute ----
// blocks 0..127 : WzT[n][k] (bf16) where Wz = W_gat @ blockdiag(W_c[0:64]); row k = bid
// block 128     : Wt[16][4], cvec[64] (ns-pool@W_c + b_gat@W_c + b_c folded)
// block 129     : avp[8][64] packed bf16 B-fragments of av16[128][16]
//                 (cols 0-3 = att_src heads, 4-7 = att_dst heads, 8-15 = 0)
__global__ __launch_bounds__(256) void k_pre_all(
        const float* __restrict__ Wg, const float* __restrict__ W_c,
        const float* __restrict__ W_edge, const float* __restrict__ att_edge,
        const float* __restrict__ b_c, const float* __restrict__ ns,
        const float* __restrict__ b_gat,
        const float* __restrict__ att_src, const float* __restrict__ att_dst,
        unsigned short* __restrict__ WzT, float* __restrict__ Wt,
        float* __restrict__ cvec, uint2* __restrict__ avp){
  int bid = blockIdx.x, tid = threadIdx.x;
  if (bid < 128){
    __shared__ float sWg[256];
    __shared__ float sWc[64*64];
    sWg[tid] = Wg[bid*256 + tid];
    for (int i = tid; i < 4096; i += 256) sWc[i] = W_c[i];
    __syncthreads();
    int h = tid >> 6, j = tid & 63;
    float s = 0.f;
    #pragma unroll 8
    for (int c = 0; c < 64; c++) s += sWg[h*64 + c] * sWc[c*64 + j];
    WzT[tid*128 + bid] = f2bf(s);      // transposed bf16 store
  } else if (bid == 128){
    if (tid < 64){
      int d = tid >> 2, h = tid & 3;
      float s = 0.f;
      for (int c = 0; c < 64; c++) s += W_edge[d*256 + h*64 + c] * att_edge[h*64 + c];
      Wt[d*4 + h] = s;
    } else if (tid < 128){
      int j = tid - 64;
      float s = b_c[j];
      for (int d = 0; d < 16; d++) s += ns[d >> 1] * W_c[(64 + d)*64 + j];
      for (int c = 0; c < 64; c++) s += b_gat[c] * W_c[c*64 + j];
      cvec[j] = s;
    }
  } else {
    __shared__ float sav2[1024];       // [k][o] o: 0-3 src, 4-7 dst
    for (int i = tid; i < 1024; i += 256){
      int k = i >> 3, o = i & 7, h = o & 3;
      const float* att = (o < 4) ? att_src : att_dst;
      float s = 0.f;
      for (int c = 0; c < 64; c++) s += Wg[k*256 + h*64 + c] * att[h*64 + c];
      sav2[i] = s;
    }
    __syncthreads();
    if (tid < 64){
      int l = tid, lg = l >> 4, lr = l & 15;
      for (int ks = 0; ks < 8; ks++){
        unsigned int h0, h1, h2, h3;
        int kb = ks*16 + lg*4;
        h0 = (lr < 8) ? f2bf(sav2[(kb+0)*8 + lr]) : 0u;
        h1 = (lr < 8) ? f2bf(sav2[(kb+1)*8 + lr]) : 0u;
        h2 = (lr < 8) ? f2bf(sav2[(kb+2)*8 + lr]) : 0u;
        h3 = (lr < 8) ? f2bf(sav2[(kb+3)*8 + lr]) : 0u;
        uint2 u; u.x = h0 | (h1 << 16); u.y = h2 | (h3 << 16);
        avp[ks*64 + l] = u;
      }
    }
  }
}

// ---- K1: zs = x @ Wz via MFMA (bf16 in, fp32 acc, bf16 out)
//          + fused a_src/a_dst MFMA + deg histogram. Zero barriers. ----
__global__ __launch_bounds__(256) void k_gemm(const float* __restrict__ x,
        const unsigned short* __restrict__ WzT, const uint2* __restrict__ avp,
        const int* __restrict__ dsts,
        __hip_bfloat16* __restrict__ zs,
        float* __restrict__ a_src, float* __restrict__ a_dst,
        u32* __restrict__ deg){
  __shared__ alignas(16) __hip_bfloat16 zt[4][16][264];   // per-wave private
  int tid = threadIdx.x;
  // deg histogram: issued first, retires under the compute below (no barrier)
  {
    int g = blockIdx.x*256 + tid;
    if (g < EE/4){
      int4 d4 = *(const int4*)(dsts + (size_t)g*4);
      atomicAdd(&deg[d4.x], 1u);
      atomicAdd(&deg[d4.y], 1u);
      atomicAdd(&deg[d4.z], 1u);
      atomicAdd(&deg[d4.w], 1u);
    }
  }
  int w = tid >> 6, l = tid & 63;
  int lr = l & 15, lg = l >> 4;
  int n0 = blockIdx.x * 64 + w*16;     // wave's 16 rows

  // A-fragments (8 K-steps of 16) + fused adot MFMA
  short4v afr[8];
  f32x4 cad = {0.f, 0.f, 0.f, 0.f};
  #pragma unroll
  for (int ks = 0; ks < 8; ks++){
    int row = n0 + lr; if (row >= NN) row = NN - 1;
    float4 xa = *(const float4*)(x + (size_t)row*128 + ks*16 + lg*4);
    short4v a;
    a[0] = (short)f2bf(xa.x); a[1] = (short)f2bf(xa.y);
    a[2] = (short)f2bf(xa.z); a[3] = (short)f2bf(xa.w);
    afr[ks] = a;
    uint2 bv = avp[ks*64 + l];
    short4v b = __builtin_bit_cast(short4v, bv);
    cad = __builtin_amdgcn_mfma_f32_16x16x16bf16_1k(afr[ks], b, cad, 0, 0, 0);
  }
  #pragma unroll
  for (int r = 0; r < 4; r++){
    int n = n0 + lg*4 + r;
    if (n < NN){
      if (lr < 4)      a_src[(size_t)n*4 + lr]       = cad[r];
      else if (lr < 8) a_dst[(size_t)n*4 + (lr - 4)] = cad[r];
    }
  }

  // main GEMM: 16 column-tiles of 16, B-frags from L2-resident WzT (64KB)
  #pragma unroll 2
  for (int t = 0; t < 16; t++){
    f32x4 c = {0.f, 0.f, 0.f, 0.f};
    #pragma unroll
    for (int ks = 0; ks < 8; ks++){
      short4v b = *(const short4v*)(WzT + ((size_t)(t*16 + lr)*128 + ks*16 + lg*4));
      c = __builtin_amdgcn_mfma_f32_16x16x16bf16_1k(afr[ks], b, c, 0, 0, 0);
    }
    #pragma unroll
    for (int r = 0; r < 4; r++)
      zt[w][lg*4 + r][t*16 + lr] = __float2bfloat16(c[r]);
  }
  // coalesced zs store from the per-wave LDS tile (16 rows x 512B)
  #pragma unroll
  for (int i = 0; i < 8; i++){
    int f = i*64 + l;
    int row = f >> 5, ch = f & 31;
    int n = n0 + row;
    if (n < NN)
      *(uint4*)(zs + (size_t)n*256 + ch*8) = *(const uint4*)&zt[w][row][ch*8];
  }
}

// ---- K3a/K3b: two-level exclusive scan of deg -> offs (+ cnt zeroing) ----
__global__ __launch_bounds__(1024) void k_scan1(const u32* __restrict__ deg,
                                                u32* __restrict__ offs, u32* __restrict__ bsum){
  __shared__ u32 sd[1024];
  int t = threadIdx.x;
  int i = blockIdx.x*1024 + t;
  u32 v = (i < NN) ? deg[i] : 0u;
  sd[t] = v; __syncthreads();
  for (int off = 1; off < 1024; off <<= 1){
    u32 u = (t >= off) ? sd[t-off] : 0u;
    __syncthreads();
    sd[t] += u;
    __syncthreads();
  }
  if (i < NN) offs[i] = sd[t] - v;
  if (t == 1023) bsum[blockIdx.x] = sd[1023];
}

__global__ __launch_bounds__(1024) void k_scan2(u32* __restrict__ offs, const u32* __restrict__ bsum,
                                                u32* __restrict__ cnt){
  int b = blockIdx.x;
  u32 p = 0;
  for (int j = 0; j < b; j++) p += bsum[j];
  int i = b*1024 + threadIdx.x;
  if (i < NN){ offs[i] += p; cnt[i] = 0u; }
  if (i == NN-1){
    u32 tot = p;
    for (int j = b; j < 49; j++) tot += bsum[j];
    offs[NN] = tot;
  }
}

// ---- K4: per-edge logits + leaky_relu, written DIRECTLY in CSR order ----
__global__ __launch_bounds__(256) void k_edge(const float* __restrict__ qraw,
        const float* __restrict__ eattr, const int* __restrict__ eidx,
        const float* __restrict__ Wq1, const float* __restrict__ bq1,
        const float* __restrict__ Wq2, const float* __restrict__ bq2,
        const float* __restrict__ Wt,
        const float* __restrict__ a_src, const float* __restrict__ a_dst,
        const u32* __restrict__ offs, u32* __restrict__ cnt,
        float* __restrict__ alpha_csr, u32* __restrict__ srcs_csr){
  __shared__ float sWq1[32], sbq1[8], sWq2[128], sbq2[16], sWt[64];
  int tid = threadIdx.x;
  if (tid < 32) sWq1[tid] = Wq1[tid];
  else if (tid < 40)  sbq1[tid-32]  = bq1[tid-32];
  else if (tid < 168) sWq2[tid-40]  = Wq2[tid-40];
  else if (tid < 184) sbq2[tid-168] = bq2[tid-168];
  else if (tid < 248) sWt[tid-184]  = Wt[tid-184];
  __syncthreads();
  int e = blockIdx.x*256 + tid;
  if (e >= EE) return;

  float4 qr = *(const float4*)(qraw + (size_t)e*4);
  float t1[8];
  #pragma unroll
  for (int j = 0; j < 8; j++){
    float s = sbq1[j] + qr.x*sWq1[j] + qr.y*sWq1[8+j] + qr.z*sWq1[16+j] + qr.w*sWq1[24+j];
    t1[j] = fmaxf(s, 0.f);
  }
  float ae[4] = {0.f,0.f,0.f,0.f};
  const float* ea = eattr + (size_t)e*16;
  #pragma unroll
  for (int d = 0; d < 16; d++){
    float q = sbq2[d];
    #pragma unroll
    for (int j = 0; j < 8; j++) q += t1[j]*sWq2[j*16 + d];
    float v = ea[d] + q;
    #pragma unroll
    for (int h = 0; h < 4; h++) ae[h] += v * sWt[d*4 + h];
  }
  int src = eidx[e], dst = eidx[EE + e];
  float4 as4 = *(const float4*)(a_src + (size_t)src*4);
  float4 ad4 = *(const float4*)(a_dst + (size_t)dst*4);
  float4 out;
  float* po = (float*)&out;
  float av4[4] = {as4.x + ad4.x + ae[0], as4.y + ad4.y + ae[1],
                  as4.z + ad4.z + ae[2], as4.w + ad4.w + ae[3]};
  #pragma unroll
  for (int hh = 0; hh < 4; hh++){
    float a = av4[hh];
    po[hh] = (a >= 0.f) ? a : NEG*a;
  }
  u32 pos = offs[dst] + atomicAdd(&cnt[dst], 1u);
  ((float4*)alpha_csr)[pos] = out;
  srcs_csr[pos] = (u32)src;
}

// ---- K5: per-node aggregation, no max subtraction (logits bounded), 4x unroll ----
__global__ __launch_bounds__(256) void k_agg(const __hip_bfloat16* __restrict__ zs,
        const u32* __restrict__ srcs_csr, const u32* __restrict__ offs,
        const float* __restrict__ alpha_csr,
        const float* __restrict__ cvec, float* __restrict__ out){
  int tid = threadIdx.x;
  int w = tid >> 6, lane = tid & 63;
  int n = blockIdx.x*4 + w;       // grid = NN/4 exactly
  int h = lane >> 4;              // this lane's head (channels lane*4..lane*4+3)
  u32 p0 = offs[n], p1 = offs[n+1];
  float d = 0.f;
  float a0 = 0.f, a1 = 0.f, a2 = 0.f, a3 = 0.f;
  u32 p = p0;
  for (; p + 4 <= p1; p += 4){
    u32 s0 = srcs_csr[p+0], s1 = srcs_csr[p+1], s2 = srcs_csr[p+2], s3 = srcs_csr[p+3];
    float al0 = alpha_csr[(size_t)(p+0)*4 + h];
    float al1 = alpha_csr[(size_t)(p+1)*4 + h];
    float al2 = alpha_csr[(size_t)(p+2)*4 + h];
    float al3 = alpha_csr[(size_t)(p+3)*4 + h];
    uint2 v0 = *(const uint2*)(zs + (size_t)s0*256 + lane*4);
    uint2 v1 = *(const uint2*)(zs + (size_t)s1*256 + lane*4);
    uint2 v2 = *(const uint2*)(zs + (size_t)s2*256 + lane*4);
    uint2 v3 = *(const uint2*)(zs + (size_t)s3*256 + lane*4);
    float w0 = __expf(al0), w1 = __expf(al1), w2 = __expf(al2), w3 = __expf(al3);
    a0 += w0*__uint_as_float(v0.x << 16)        + w1*__uint_as_float(v1.x << 16)
        + w2*__uint_as_float(v2.x << 16)        + w3*__uint_as_float(v3.x << 16);
    a1 += w0*__uint_as_float(v0.x & 0xffff0000u)+ w1*__uint_as_float(v1.x & 0xffff0000u)
        + w2*__uint_as_float(v2.x & 0xffff0000u)+ w3*__uint_as_float(v3.x & 0xffff0000u);
    a2 += w0*__uint_as_float(v0.y << 16)        + w1*__uint_as_float(v1.y << 16)
        + w2*__uint_as_float(v2.y << 16)        + w3*__uint_as_float(v3.y << 16);
    a3 += w0*__uint_as_float(v0.y & 0xffff0000u)+ w1*__uint_as_float(v1.y & 0xffff0000u)
        + w2*__uint_as_float(v2.y & 0xffff0000u)+ w3*__uint_as_float(v3.y & 0xffff0000u);
    d  += (w0 + w1) + (w2 + w3);
  }
  for (; p < p1; p++){
    u32 s0 = srcs_csr[p];
    float al = alpha_csr[(size_t)p*4 + h];
    uint2 v0 = *(const uint2*)(zs + (size_t)s0*256 + lane*4);
    float w0 = __expf(al);
    a0 += w0*__uint_as_float(v0.x << 16);
    a1 += w0*__uint_as_float(v0.x & 0xffff0000u);
    a2 += w0*__uint_as_float(v0.y << 16);
    a3 += w0*__uint_as_float(v0.y & 0xffff0000u);
    d  += w0;
  }
  float inv = (d > 0.f) ? 0.25f / d : 0.f;
  a0 *= inv; a1 *= inv; a2 *= inv; a3 *= inv;
  a0 += __shfl_xor(a0, 16); a1 += __shfl_xor(a1, 16);
  a2 += __shfl_xor(a2, 16); a3 += __shfl_xor(a3, 16);
  a0 += __shfl_xor(a0, 32); a1 += __shfl_xor(a1, 32);
  a2 += __shfl_xor(a2, 32); a3 += __shfl_xor(a3, 32);
  if (lane < 16){
    float4 cv = *(const float4*)(cvec + lane*4);
    float4 o4;
    o4.x = fmaxf(a0 + cv.x, 0.f);
    o4.y = fmaxf(a1 + cv.y, 0.f);
    o4.z = fmaxf(a2 + cv.z, 0.f);
    o4.w = fmaxf(a3 + cv.w, 0.f);
    *(float4*)(out + (size_t)n*64 + lane*4) = o4;
  }
}

extern "C" void kernel_launch(void* const* d_in, const int* in_sizes, int n_in,
                              void* d_out, int out_size, void* d_ws, size_t ws_size,
                              hipStream_t stream){
  const float* x       = (const float*)d_in[0];
  const int*   eidx    = (const int*)d_in[1];
  const float* eattr   = (const float*)d_in[2];
  const float* qraw    = (const float*)d_in[3];
  const float* ns      = (const float*)d_in[4];
  const float* Wg      = (const float*)d_in[5];
  const float* att_src = (const float*)d_in[6];
  const float* att_dst = (const float*)d_in[7];
  const float* W_edge  = (const float*)d_in[8];
  const float* att_edge= (const float*)d_in[9];
  const float* b_gat   = (const float*)d_in[10];
  const float* Wq1     = (const float*)d_in[11];
  const float* bq1     = (const float*)d_in[12];
  const float* Wq2     = (const float*)d_in[13];
  const float* bq2     = (const float*)d_in[14];
  const float* W_c     = (const float*)d_in[15];
  const float* b_c     = (const float*)d_in[16];
  float* out = (float*)d_out;

  char* ws = (char*)d_ws;
  __hip_bfloat16* zs = (__hip_bfloat16*)ws;            // 25,600,000 B
  float* a_src    = (float*)(ws + 25600000);           //    800,000 B
  float* a_dst    = (float*)(ws + 26400000);           //    800,000 B
  float* alpha_csr= (float*)(ws + 27200000);           // 12,800,000 B
  u32* srcs_csr   = (u32*)(ws + 40000000);             //  3,200,000 B
  u32* deg        = (u32*)(ws + 43200000);             //    200,000 B
  u32* offs       = (u32*)(ws + 43400000);             //    200,064 B
  u32* cnt        = (u32*)(ws + 43600064);             //    200,000 B
  u32* bsum       = (u32*)(ws + 43800064);             //        256 B
  float* Wt       = (float*)(ws + 43800320);           //        256 B
  float* cvec     = (float*)(ws + 43800576);           //        256 B
  unsigned short* WzT = (unsigned short*)(ws + 43800832); //  65,536 B
  uint2* avp      = (uint2*)(ws + 43866368);           //      4,096 B

  hipMemsetAsync(deg, 0, 200000, stream);

  k_pre_all<<<130,  256, 0, stream>>>(Wg, W_c, W_edge, att_edge, b_c, ns, b_gat,
                                      att_src, att_dst, WzT, Wt, cvec, avp);
  k_gemm   <<<782,  256, 0, stream>>>(x, WzT, avp, eidx + EE, zs, a_src, a_dst, deg);
  k_scan1  <<<49,  1024, 0, stream>>>(deg, offs, bsum);
  k_scan2  <<<49,  1024, 0, stream>>>(offs, bsum, cnt);
  k_edge   <<<3125, 256, 0, stream>>>(qraw, eattr, eidx, Wq1, bq1, Wq2, bq2, Wt,
                                      a_src, a_dst, offs, cnt, alpha_csr, srcs_csr);
  k_agg    <<<12500,256, 0, stream>>>(zs, srcs_csr, offs, alpha_csr, cvec, out);
}